// Round 1
// baseline (6948.225 us; speedup 1.0000x reference)
//
#include <hip/hip_runtime.h>

// BranchingGNN: bipartite message passing, 2 rounds.
//   h_item = relu(item_feat @ W_item + b_item)            [n,128]
//   h_pat  = relu(pattern_feat @ W_pat + b_pat)           [m,128]
//   round x2:
//     p_msg = segsum(h_item[i_idx] -> p_idx, m); h_pat = relu(h_pat + relu(p_msg@W_i2p+b))
//     i_msg = segsum(h_pat[p_idx] -> i_idx, n); h_item = relu(h_item + relu(i_msg@W_p2i+b))
// Output: h_item ‖ h_pat flat (computed in-place in d_out).

static constexpr int HDIM = 128;

// out[r,j] = relu(sum_k X[r,k]*W[k,j] + b[j]); K = input dim, R rows/block.
template<int K, int R>
__global__ __launch_bounds__(128) void gemm_relu_kernel(
    const float* __restrict__ X, const float* __restrict__ W,
    const float* __restrict__ b, float* __restrict__ out, int nrows)
{
    __shared__ float xs[R][K];
    const int j = threadIdx.x;              // output column 0..127
    const int r0 = blockIdx.x * R;
    const int total = R * K;
    for (int t = j; t < total; t += 128) {
        const int rr = t / K, kk = t % K;
        const int r = r0 + rr;
        xs[rr][kk] = (r < nrows) ? X[(size_t)r * K + kk] : 0.f;
    }
    __syncthreads();
    float acc[R];
    const float bj = b[j];
    #pragma unroll
    for (int i = 0; i < R; ++i) acc[i] = bj;
    #pragma unroll 8
    for (int k = 0; k < K; ++k) {
        const float w = W[k * HDIM + j];    // coalesced across j; L2-resident
        #pragma unroll
        for (int i = 0; i < R; ++i) acc[i] = fmaf(xs[i][k], w, acc[i]);
    }
    #pragma unroll
    for (int i = 0; i < R; ++i) {
        const int r = r0 + i;
        if (r < nrows) out[(size_t)r * HDIM + j] = fmaxf(acc[i], 0.f);
    }
}

// hstate[r,j] = relu(hstate[r,j] + relu(sum_k Msg[r,k]*W[k,j] + b[j]))
template<int R>
__global__ __launch_bounds__(128) void update_kernel(
    const float* __restrict__ Msg, const float* __restrict__ W,
    const float* __restrict__ b, float* __restrict__ hstate, int nrows)
{
    __shared__ float xs[R][HDIM];
    const int j = threadIdx.x;
    const int r0 = blockIdx.x * R;
    const int total = R * HDIM;
    for (int t = j; t < total; t += 128) {
        const int rr = t / HDIM, kk = t % HDIM;
        const int r = r0 + rr;
        xs[rr][kk] = (r < nrows) ? Msg[(size_t)r * HDIM + kk] : 0.f;
    }
    __syncthreads();
    float acc[R];
    const float bj = b[j];
    #pragma unroll
    for (int i = 0; i < R; ++i) acc[i] = bj;
    #pragma unroll 8
    for (int k = 0; k < HDIM; ++k) {
        const float w = W[k * HDIM + j];
        #pragma unroll
        for (int i = 0; i < R; ++i) acc[i] = fmaf(xs[i][k], w, acc[i]);
    }
    #pragma unroll
    for (int i = 0; i < R; ++i) {
        const int r = r0 + i;
        if (r < nrows) {
            const float msg = fmaxf(acc[i], 0.f);
            const float hs = hstate[(size_t)r * HDIM + j];
            hstate[(size_t)r * HDIM + j] = fmaxf(hs + msg, 0.f);
        }
    }
}

// For each edge e: dst[dst_idx[e], :] += src[src_idx[e], :]   (128 floats)
// 32 lanes per edge, float4 per lane, hardware f32 atomics.
__global__ __launch_bounds__(256) void scatter_add_kernel(
    const float* __restrict__ src, const int* __restrict__ src_idx,
    const int* __restrict__ dst_idx, float* __restrict__ dst, int E)
{
    const int t = blockIdx.x * 256 + threadIdx.x;
    const int e = t >> 5;
    if (e >= E) return;
    const int lane = t & 31;
    const int s = src_idx[e];
    const int d = dst_idx[e];
    const float4 v = ((const float4*)(src + (size_t)s * HDIM))[lane];
    float* drow = dst + (size_t)d * HDIM + lane * 4;
    unsafeAtomicAdd(drow + 0, v.x);
    unsafeAtomicAdd(drow + 1, v.y);
    unsafeAtomicAdd(drow + 2, v.z);
    unsafeAtomicAdd(drow + 3, v.w);
}

extern "C" void kernel_launch(void* const* d_in, const int* in_sizes, int n_in,
                              void* d_out, int out_size, void* d_ws, size_t ws_size,
                              hipStream_t stream)
{
    const float* item_feat = (const float*)d_in[0];   // [n,64]
    const float* pat_feat  = (const float*)d_in[1];   // [m,64]
    const int*   i_idx     = (const int*)d_in[2];     // [E]
    const int*   p_idx     = (const int*)d_in[3];     // [E]
    const float* W_item    = (const float*)d_in[4];   // [64,128]
    const float* b_item    = (const float*)d_in[5];
    const float* W_pat     = (const float*)d_in[6];
    const float* b_pat     = (const float*)d_in[7];
    const float* W_i2p     = (const float*)d_in[8];   // [128,128]
    const float* b_i2p     = (const float*)d_in[9];
    const float* W_p2i     = (const float*)d_in[10];
    const float* b_p2i     = (const float*)d_in[11];

    const int n = in_sizes[0] / 64;
    const int m = in_sizes[1] / 64;
    const int E = in_sizes[2];

    float* h_item = (float*)d_out;                       // [n,128]
    float* h_pat  = (float*)d_out + (size_t)n * HDIM;    // [m,128]
    float* p_msg  = (float*)d_ws;                        // [m,128]
    float* i_msg  = (float*)d_ws + (size_t)m * HDIM;     // [n,128]

    constexpr int R = 4;
    gemm_relu_kernel<64, R><<<(n + R - 1) / R, 128, 0, stream>>>(
        item_feat, W_item, b_item, h_item, n);
    gemm_relu_kernel<64, R><<<(m + R - 1) / R, 128, 0, stream>>>(
        pat_feat, W_pat, b_pat, h_pat, m);

    const int scatter_blocks = (E * 32 + 255) / 256;
    for (int round = 0; round < 2; ++round) {
        hipMemsetAsync(d_ws, 0, (size_t)(n + m) * HDIM * sizeof(float), stream);
        // item -> pattern
        scatter_add_kernel<<<scatter_blocks, 256, 0, stream>>>(
            h_item, i_idx, p_idx, p_msg, E);
        update_kernel<R><<<(m + R - 1) / R, 128, 0, stream>>>(
            p_msg, W_i2p, b_i2p, h_pat, m);
        // pattern -> item
        scatter_add_kernel<<<scatter_blocks, 256, 0, stream>>>(
            h_pat, p_idx, i_idx, i_msg, E);
        update_kernel<R><<<(n + R - 1) / R, 128, 0, stream>>>(
            i_msg, W_p2i, b_p2i, h_item, n);
    }
}

// Round 2
// 1012.747 us; speedup vs baseline: 6.8608x; 6.8608x over previous
//
#include <hip/hip_runtime.h>

// BranchingGNN: bipartite message passing, 2 rounds. fp32 throughout.
// R2 strategy: replace 512M-f32-atomic scatter (2 GB HBM write-through, 1677 µs
// per dispatch in R1) with device-built CSR + gather. CSR built once per launch,
// reused across both rounds. Gather fused with the H×H GEMM + relu + residual.

static constexpr int HDIM = 128;

// ---------------- initial projection: out = relu(X @ W + b), K=64 -------------
template<int K, int R>
__global__ __launch_bounds__(128) void gemm_relu_kernel(
    const float* __restrict__ X, const float* __restrict__ W,
    const float* __restrict__ b, float* __restrict__ out, int nrows)
{
    __shared__ float xs[R][K];
    const int j = threadIdx.x;
    const int r0 = blockIdx.x * R;
    const int total = R * K;
    for (int t = j; t < total; t += 128) {
        const int rr = t / K, kk = t % K;
        const int r = r0 + rr;
        xs[rr][kk] = (r < nrows) ? X[(size_t)r * K + kk] : 0.f;
    }
    __syncthreads();
    float acc[R];
    const float bj = b[j];
    #pragma unroll
    for (int i = 0; i < R; ++i) acc[i] = bj;
    #pragma unroll 8
    for (int k = 0; k < K; ++k) {
        const float w = W[k * HDIM + j];
        #pragma unroll
        for (int i = 0; i < R; ++i) acc[i] = fmaf(xs[i][k], w, acc[i]);
    }
    #pragma unroll
    for (int i = 0; i < R; ++i) {
        const int r = r0 + i;
        if (r < nrows) out[(size_t)r * HDIM + j] = fmaxf(acc[i], 0.f);
    }
}

// ---------------- CSR build ---------------------------------------------------
__global__ __launch_bounds__(256) void count_kernel(
    const int* __restrict__ i_idx, const int* __restrict__ p_idx,
    int* __restrict__ cnt_i, int* __restrict__ cnt_p, int E)
{
    const int e = blockIdx.x * 256 + threadIdx.x;
    if (e >= E) return;
    atomicAdd(&cnt_p[p_idx[e]], 1);
    atomicAdd(&cnt_i[i_idx[e]], 1);
}

// Single-block exclusive scan (Hillis-Steele over LDS, sequential chunks).
// out has len+1 entries; out[len] = total.
template<int BS>
__global__ __launch_bounds__(BS) void exscan_kernel(
    const int* __restrict__ in, int* __restrict__ out, int len)
{
    __shared__ int buf[BS];
    __shared__ int carry_s;
    const int tid = threadIdx.x;
    if (tid == 0) carry_s = 0;
    for (int base = 0; base < len; base += BS) {
        const int i = base + tid;
        const int v = (i < len) ? in[i] : 0;
        __syncthreads();                 // protect buf & carry from prev iter
        buf[tid] = v;
        __syncthreads();
        #pragma unroll
        for (int off = 1; off < BS; off <<= 1) {
            const int t = (tid >= off) ? buf[tid - off] : 0;
            __syncthreads();
            buf[tid] += t;
            __syncthreads();
        }
        const int incl = buf[tid];
        const int total = buf[BS - 1];
        if (i < len) out[i] = carry_s + incl - v;   // exclusive
        __syncthreads();                 // everyone read carry_s
        if (tid == 0) carry_s += total;
    }
    __syncthreads();
    if (tid == 0) out[len] = carry_s;
}

__global__ __launch_bounds__(256) void fill_kernel(
    const int* __restrict__ i_idx, const int* __restrict__ p_idx,
    const int* __restrict__ row_p, const int* __restrict__ row_i,
    int* __restrict__ cur_p, int* __restrict__ cur_i,
    int* __restrict__ esrc_p, int* __restrict__ esrc_i, int E)
{
    const int e = blockIdx.x * 256 + threadIdx.x;
    if (e >= E) return;
    const int ii = i_idx[e], pp = p_idx[e];
    const int sp = atomicAdd(&cur_p[pp], 1);
    esrc_p[row_p[pp] + sp] = ii;         // pattern <- item edges, grouped by pattern
    const int si = atomicAdd(&cur_i[ii], 1);
    esrc_i[row_i[ii] + si] = pp;         // item <- pattern edges, grouped by item
}

// ---------------- fused gather + GEMM + relu + residual + relu ----------------
// Block = 128 threads (thread j owns column j), R destination rows per block.
// msg[r] = sum over CSR edge list of src rows; then
// hdst[d] = relu(hdst[d] + relu(msg @ W + b)).  Handles deg==0 (msg=0 -> relu(b)).
template<int R>
__global__ __launch_bounds__(128) void gather_update_kernel(
    const float* __restrict__ src, const int* __restrict__ row,
    const int* __restrict__ esrc, const float* __restrict__ W,
    const float* __restrict__ b, float* __restrict__ hdst, int ndst)
{
    __shared__ float msg[R][HDIM];
    const int j = threadIdx.x;
    const int d0 = blockIdx.x * R;
    #pragma unroll
    for (int r = 0; r < R; ++r) {
        const int d = d0 + r;
        float acc = 0.f;
        if (d < ndst) {
            const int s0 = row[d], s1 = row[d + 1];
            for (int e = s0; e < s1; ++e) {
                acc += src[(size_t)esrc[e] * HDIM + j];   // coalesced 512B/iter
            }
        }
        msg[r][j] = acc;
    }
    __syncthreads();
    float out[R];
    const float bj = b[j];
    #pragma unroll
    for (int r = 0; r < R; ++r) out[r] = bj;
    #pragma unroll 4
    for (int k = 0; k < HDIM; ++k) {
        const float w = W[k * HDIM + j];      // coalesced; reused across R rows
        #pragma unroll
        for (int r = 0; r < R; ++r) out[r] = fmaf(msg[r][k], w, out[r]);
    }
    #pragma unroll
    for (int r = 0; r < R; ++r) {
        const int d = d0 + r;
        if (d < ndst) {
            const float upd = fmaxf(out[r], 0.f);
            const float h = hdst[(size_t)d * HDIM + j];
            hdst[(size_t)d * HDIM + j] = fmaxf(h + upd, 0.f);
        }
    }
}

extern "C" void kernel_launch(void* const* d_in, const int* in_sizes, int n_in,
                              void* d_out, int out_size, void* d_ws, size_t ws_size,
                              hipStream_t stream)
{
    const float* item_feat = (const float*)d_in[0];   // [n,64]
    const float* pat_feat  = (const float*)d_in[1];   // [m,64]
    const int*   i_idx     = (const int*)d_in[2];     // [E]
    const int*   p_idx     = (const int*)d_in[3];     // [E]
    const float* W_item    = (const float*)d_in[4];
    const float* b_item    = (const float*)d_in[5];
    const float* W_pat     = (const float*)d_in[6];
    const float* b_pat     = (const float*)d_in[7];
    const float* W_i2p     = (const float*)d_in[8];
    const float* b_i2p     = (const float*)d_in[9];
    const float* W_p2i     = (const float*)d_in[10];
    const float* b_p2i     = (const float*)d_in[11];

    const int n = in_sizes[0] / 64;
    const int m = in_sizes[1] / 64;
    const int E = in_sizes[2];

    float* h_item = (float*)d_out;                    // [n,128]
    float* h_pat  = (float*)d_out + (size_t)n * HDIM; // [m,128]

    // workspace layout (ints): [cur_p m][cur_i n][row_p m+1][row_i n+1][esrc_p E][esrc_i E]
    int* cur_p  = (int*)d_ws;
    int* cur_i  = cur_p + m;
    int* row_p  = cur_i + n;
    int* row_i  = row_p + (m + 1);
    int* esrc_p = row_i + (n + 1);
    int* esrc_i = esrc_p + E;

    constexpr int RG = 4;   // rows/block for init gemm
    gemm_relu_kernel<64, RG><<<(n + RG - 1) / RG, 128, 0, stream>>>(
        item_feat, W_item, b_item, h_item, n);
    gemm_relu_kernel<64, RG><<<(m + RG - 1) / RG, 128, 0, stream>>>(
        pat_feat, W_pat, b_pat, h_pat, m);

    // ---- CSR build (once; index arrays are static across rounds) ----
    const int eblocks = (E + 255) / 256;
    hipMemsetAsync(cur_p, 0, (size_t)(m + n) * sizeof(int), stream);
    count_kernel<<<eblocks, 256, 0, stream>>>(i_idx, p_idx, cur_i, cur_p, E);
    exscan_kernel<1024><<<1, 1024, 0, stream>>>(cur_p, row_p, m);
    exscan_kernel<1024><<<1, 1024, 0, stream>>>(cur_i, row_i, n);
    hipMemsetAsync(cur_p, 0, (size_t)(m + n) * sizeof(int), stream);
    fill_kernel<<<eblocks, 256, 0, stream>>>(i_idx, p_idx, row_p, row_i,
                                             cur_p, cur_i, esrc_p, esrc_i, E);

    // ---- 2 rounds of fused gather+GEMM+update, no atomics, no msg buffers ----
    constexpr int R = 8;
    for (int round = 0; round < 2; ++round) {
        gather_update_kernel<R><<<(m + R - 1) / R, 128, 0, stream>>>(
            h_item, row_p, esrc_p, W_i2p, b_i2p, h_pat, m);
        gather_update_kernel<R><<<(n + R - 1) / R, 128, 0, stream>>>(
            h_pat, row_i, esrc_i, W_p2i, b_p2i, h_item, n);
    }
}